// Round 3
// baseline (632.308 us; speedup 1.0000x reference)
//
#include <hip/hip_runtime.h>
#include <hip/hip_fp16.h>

// ---------------------------------------------------------------------------
// Ctx_MHAtt: out = ((softmax(LN_k((QE·KH^T)))) · VH) · Wm^T + bm
// where QE = (q·Wq^T + bq + tanh(tau)·CU) * (1/sqrt(128))/(1+tanh(tau))
//       CU = Wup · (c·Wc^T + bc)   (caption upsample KC=32 -> NQ)
// B=8, NQ=NK=HD=1024, H=8, HS=128, KC=32
// (Resubmission: rounds 1-2 were infra failures; kernel never ran.)
// ---------------------------------------------------------------------------

typedef _Float16 f16;
typedef _Float16 f16x8 __attribute__((ext_vector_type(8)));
typedef _Float16 f16x4 __attribute__((ext_vector_type(4)));
typedef float    f32x4 __attribute__((ext_vector_type(4)));

#define B_  8
#define NQ_ 1024
#define NK_ 1024
#define HD_ 1024
#define H_  8
#define HS_ 128
#define KC_ 32

__device__ __forceinline__ void g2lds16(const void* g, void* l) {
    __builtin_amdgcn_global_load_lds((const __attribute__((address_space(1))) void*)g,
                                     (__attribute__((address_space(3))) void*)l, 16, 0, 0);
}

// --------------------------- ws-too-small sentinel ---------------------------
__global__ __launch_bounds__(256) void fill_sentinel(float* __restrict__ out, int n) {
    int i = blockIdx.x * 256 + threadIdx.x;
    if (i < n) out[i] = 12345.0f;
}

// --------------------------- fp32 -> fp16 convert ---------------------------
__global__ __launch_bounds__(256) void cvt_f32_f16(const float* __restrict__ in,
                                                   f16* __restrict__ out, int n4) {
    int i = blockIdx.x * 256 + threadIdx.x;
    if (i >= n4) return;
    float4 v = ((const float4*)in)[i];
    f16x4 o;
    o[0] = (f16)v.x; o[1] = (f16)v.y; o[2] = (f16)v.z; o[3] = (f16)v.w;
    ((f16x4*)out)[i] = o;
}

// --------------------------- NT GEMM: C = A · B^T ---------------------------
// A:[M,K] f16 row-major, B:[N,K] f16 row-major, per-batch strides (elements).
// MODE 0: fp32 out, +bias[col]   (CH; M may be < 128 -> clamp+guard)
// MODE 1: f16  out, +bias[col]   (KH)
// MODE 2: f16  out, +bias[row]   (VT: rows are hd, cols are key)
// MODE 3: f16  out, (acc+bias[col]+t*extra)*scale  (QE; extra is f16)
// MODE 4: fp32 out, +bias[col]   (final output)
template <int MODE>
__global__ __launch_bounds__(256) void gemm_nt(
    const f16* __restrict__ A, long long sA,
    const f16* __restrict__ B, long long sB,
    void* __restrict__ Cv, long long sC,
    int M, int N, int K,
    const float* __restrict__ bias,
    const f16* __restrict__ extra, long long sE,
    const float* __restrict__ taup)
{
    __shared__ __align__(16) f16 As[128 * 32];
    __shared__ __align__(16) f16 Bs[128 * 32];
    const int bz = blockIdx.z;
    const f16* Ab = A + (size_t)bz * sA;
    const f16* Bb = B + (size_t)bz * sB;
    const int row0 = blockIdx.y * 128, col0 = blockIdx.x * 128;
    const int tid = threadIdx.x, wave = tid >> 6, lane = tid & 63;
    const int g = lane >> 4, li = lane & 15;
    const int wr = wave >> 1, wc = wave & 1;

    f32x4 acc[4][4];
#pragma unroll
    for (int i = 0; i < 4; i++)
#pragma unroll
        for (int j = 0; j < 4; j++) acc[i][j] = (f32x4){0.f, 0.f, 0.f, 0.f};

    for (int k0 = 0; k0 < K; k0 += 32) {
#pragma unroll
        for (int i = 0; i < 2; i++) {
            int slot = i * 256 + tid;          // 16B slot in [0,512)
            int rr = slot >> 2, cc8 = (slot & 3) << 3;
            int ra = row0 + rr;
            if (MODE == 0 && ra >= M) ra = M - 1;   // clamp (stores guarded)
            g2lds16(Ab + (size_t)ra * K + k0 + cc8, As + (size_t)(i * 256 + wave * 64) * 8);
            g2lds16(Bb + (size_t)(col0 + rr) * K + k0 + cc8, Bs + (size_t)(i * 256 + wave * 64) * 8);
        }
        __syncthreads();   // drains vmcnt(0): LDS tiles ready
        f16x8 af[4], bf[4];
#pragma unroll
        for (int i = 0; i < 4; i++) af[i] = *(const f16x8*)&As[(wr * 64 + i * 16 + li) * 32 + g * 8];
#pragma unroll
        for (int j = 0; j < 4; j++) bf[j] = *(const f16x8*)&Bs[(wc * 64 + j * 16 + li) * 32 + g * 8];
#pragma unroll
        for (int i = 0; i < 4; i++)
#pragma unroll
            for (int j = 0; j < 4; j++)
                acc[i][j] = __builtin_amdgcn_mfma_f32_16x16x32_f16(af[i], bf[j], acc[i][j], 0, 0, 0);
        __syncthreads();   // protect LDS before next stage
    }

    float tv = 0.f, qscale = 0.f;
    if constexpr (MODE == 3) {
        tv = tanhf(taup[0]);
        qscale = 0.08838834764831845f / (1.0f + tv);   // (1/sqrt(128)) / (1+t)
    }
#pragma unroll
    for (int i = 0; i < 4; i++) {
#pragma unroll
        for (int j = 0; j < 4; j++) {
            int cc = col0 + wc * 64 + j * 16 + li;
            float bcol = (MODE == 2) ? 0.f : bias[cc];
#pragma unroll
            for (int r = 0; r < 4; r++) {
                int row = row0 + wr * 64 + i * 16 + g * 4 + r;
                if (MODE == 0 && row >= M) continue;
                float v = acc[i][j][r];
                if constexpr (MODE == 2) v += bias[row]; else v += bcol;
                size_t idx = (size_t)bz * sC + (size_t)row * N + cc;
                if constexpr (MODE == 0) ((float*)Cv)[idx] = v;
                else if constexpr (MODE == 1 || MODE == 2) ((f16*)Cv)[idx] = (f16)v;
                else if constexpr (MODE == 3) {
                    v = (v + tv * (float)extra[(size_t)bz * sE + (size_t)row * N + cc]) * qscale;
                    ((f16*)Cv)[idx] = (f16)v;
                } else ((float*)Cv)[idx] = v;   // MODE 4
            }
        }
    }
}

// --------------------------- caption upsample ---------------------------
// CU[b][u][hd] = sum_c Wup[u][c] * CH[b][c][hd]  (output f16)
__global__ __launch_bounds__(256) void upsample_k(const float* __restrict__ Wup,
                                                  const float* __restrict__ CH,
                                                  f16* __restrict__ CU) {
    const int u = blockIdx.x, b = blockIdx.y;
    const float* ch = CH + (size_t)b * KC_ * HD_;
    float w[KC_];
#pragma unroll
    for (int c = 0; c < KC_; c++) w[c] = Wup[u * KC_ + c];
    f16* out = CU + ((size_t)b * NQ_ + u) * HD_;
#pragma unroll
    for (int t = 0; t < 4; t++) {
        int i = threadIdx.x + t * 256;
        float acc = 0.f;
#pragma unroll
        for (int c = 0; c < KC_; c++) acc += w[c] * ch[c * HD_ + i];
        out[i] = (f16)acc;
    }
}

// --------------------------- fused attention ---------------------------
// grid (NQ/16, H, B); 256 threads = 4 waves; wave w owns keys [w*256, w*256+256).
// S (16 x 1024) lives in registers; LN over keys + softmax via shfl + LDS
// cross-wave reduction; P -> swizzled LDS fp16; PV from LDS x VT (key-major).
__global__ __launch_bounds__(256) void attn_k(
    const f16* __restrict__ QE,   // [B,NQ,HD]  (scaled effective query)
    const f16* __restrict__ KH,   // [B,NK,HD]
    const f16* __restrict__ VT,   // [B,HD,NK]  (v-heads transposed)
    const float* __restrict__ lnw_g, const float* __restrict__ lnb_g,
    f16* __restrict__ ATT)        // [B,NQ,HD]
{
    __shared__ __align__(16) float lnw[NK_], lnb[NK_];
    __shared__ __align__(16) f16 Plds[16 * NK_];   // 32KB, XOR-swizzled 16B chunks
    __shared__ float redS[4][16], redQ[4][16], redM[4][16], redL[4][16];

    const int tid = threadIdx.x;
    const int wave = tid >> 6, lane = tid & 63, g = lane >> 4, li = lane & 15;
    const int b = blockIdx.z, h = blockIdx.y, q0 = blockIdx.x * 16;

    for (int i = tid; i < NK_; i += 256) { lnw[i] = lnw_g[i]; lnb[i] = lnb_g[i]; }

    // Q fragments: A_op row = li, k = g*8 + j within each 32-wide k-step
    const f16* qp = QE + (size_t)(b * NQ_ + q0 + li) * HD_ + h * HS_ + g * 8;
    f16x8 a[4];
#pragma unroll
    for (int ks = 0; ks < 4; ks++) a[ks] = *(const f16x8*)(qp + ks * 32);

    // S = QE · KH^T for this wave's 256 keys
    const f16* kp = KH + (size_t)(b * NK_ + wave * 256 + li) * HD_ + h * HS_ + g * 8;
    f32x4 s[16];
#pragma unroll
    for (int j = 0; j < 16; j++) {
        f32x4 acc = (f32x4){0.f, 0.f, 0.f, 0.f};
#pragma unroll
        for (int ks = 0; ks < 4; ks++) {
            f16x8 kb = *(const f16x8*)(kp + (size_t)j * 16 * HD_ + ks * 32);
            acc = __builtin_amdgcn_mfma_f32_16x16x32_f16(a[ks], kb, acc, 0, 0, 0);
        }
        s[j] = acc;
    }
    // lane holds S[row=g*4+r][key=wave*256+j*16+li]

    // ---- mean / var over keys ----
    float ps[4] = {0, 0, 0, 0}, pq[4] = {0, 0, 0, 0};
#pragma unroll
    for (int j = 0; j < 16; j++)
#pragma unroll
        for (int r = 0; r < 4; r++) { float x = s[j][r]; ps[r] += x; pq[r] += x * x; }
#pragma unroll
    for (int m = 1; m < 16; m <<= 1)
#pragma unroll
        for (int r = 0; r < 4; r++) { ps[r] += __shfl_xor(ps[r], m, 64); pq[r] += __shfl_xor(pq[r], m, 64); }
    if (li == 0)
#pragma unroll
        for (int r = 0; r < 4; r++) { redS[wave][g * 4 + r] = ps[r]; redQ[wave][g * 4 + r] = pq[r]; }
    __syncthreads();

    float mu[4], rs[4];
#pragma unroll
    for (int r = 0; r < 4; r++) {
        int row = g * 4 + r;
        float s1 = redS[0][row] + redS[1][row] + redS[2][row] + redS[3][row];
        float s2 = redQ[0][row] + redQ[1][row] + redQ[2][row] + redQ[3][row];
        float m_ = s1 * (1.f / 1024.f);
        mu[r] = m_;
        rs[r] = rsqrtf(s2 * (1.f / 1024.f) - m_ * m_ + 1e-5f);
    }

    // ---- LayerNorm (per-key affine) + row max ----
    float mx[4] = {-1e30f, -1e30f, -1e30f, -1e30f};
#pragma unroll
    for (int j = 0; j < 16; j++) {
        int key = wave * 256 + j * 16 + li;
        float w_ = lnw[key], b_ = lnb[key];
#pragma unroll
        for (int r = 0; r < 4; r++) {
            float x = (s[j][r] - mu[r]) * rs[r] * w_ + b_;
            s[j][r] = x;
            mx[r] = fmaxf(mx[r], x);
        }
    }
#pragma unroll
    for (int m = 1; m < 16; m <<= 1)
#pragma unroll
        for (int r = 0; r < 4; r++) mx[r] = fmaxf(mx[r], __shfl_xor(mx[r], m, 64));
    if (li == 0)
#pragma unroll
        for (int r = 0; r < 4; r++) redM[wave][g * 4 + r] = mx[r];
    __syncthreads();
#pragma unroll
    for (int r = 0; r < 4; r++) {
        int row = g * 4 + r;
        mx[r] = fmaxf(fmaxf(redM[0][row], redM[1][row]), fmaxf(redM[2][row], redM[3][row]));
    }

    // ---- exp + row sum; write P (fp16) to swizzled LDS ----
    float sm[4] = {0, 0, 0, 0};
#pragma unroll
    for (int j = 0; j < 16; j++)
#pragma unroll
        for (int r = 0; r < 4; r++) { float e = __expf(s[j][r] - mx[r]); s[j][r] = e; sm[r] += e; }
#pragma unroll
    for (int m = 1; m < 16; m <<= 1)
#pragma unroll
        for (int r = 0; r < 4; r++) sm[r] += __shfl_xor(sm[r], m, 64);
    if (li == 0)
#pragma unroll
        for (int r = 0; r < 4; r++) redL[wave][g * 4 + r] = sm[r];
#pragma unroll
    for (int j = 0; j < 16; j++) {
        int key = wave * 256 + j * 16 + li;
        int chunk = key >> 3, sub = key & 7;
#pragma unroll
        for (int r = 0; r < 4; r++) {
            int row = g * 4 + r;
            Plds[row * NK_ + ((chunk ^ (row & 7)) << 3) + sub] = (f16)s[j][r];
        }
    }
    __syncthreads();

    float ls[4];
#pragma unroll
    for (int r = 0; r < 4; r++) {
        int row = g * 4 + r;
        ls[r] = redL[0][row] + redL[1][row] + redL[2][row] + redL[3][row];
    }

    // ---- PV: O[16][128], wave owns d in [wave*32, wave*32+32) ----
    const f16* vp = VT + (size_t)(b * HD_ + h * HS_ + wave * 32 + li) * NK_ + g * 8;
    f32x4 o0 = (f32x4){0.f, 0.f, 0.f, 0.f}, o1 = o0;
#pragma unroll
    for (int ks = 0; ks < 32; ks++) {
        f16x8 pa = *(const f16x8*)&Plds[li * NK_ + (((ks * 4 + g) ^ (li & 7)) << 3)];
        f16x8 v0 = *(const f16x8*)(vp + ks * 32);
        f16x8 v1 = *(const f16x8*)(vp + (size_t)16 * NK_ + ks * 32);
        o0 = __builtin_amdgcn_mfma_f32_16x16x32_f16(pa, v0, o0, 0, 0, 0);
        o1 = __builtin_amdgcn_mfma_f32_16x16x32_f16(pa, v1, o1, 0, 0, 0);
    }

    f16* op = ATT + (size_t)(b * NQ_ + q0) * HD_ + h * HS_ + wave * 32 + li;
#pragma unroll
    for (int r = 0; r < 4; r++) {
        int row = g * 4 + r;
        float inv = 1.f / ls[r];
        op[(size_t)row * HD_] = (f16)(o0[r] * inv);
        op[(size_t)row * HD_ + 16] = (f16)(o1[r] * inv);
    }
}

// --------------------------- launcher ---------------------------
extern "C" void kernel_launch(void* const* d_in, const int* in_sizes, int n_in,
                              void* d_out, int out_size, void* d_ws, size_t ws_size,
                              hipStream_t stream) {
    const float* v   = (const float*)d_in[0];
    const float* k   = (const float*)d_in[1];
    const float* q   = (const float*)d_in[2];
    const float* c   = (const float*)d_in[3];
    const float* Wv  = (const float*)d_in[4];
    const float* bv  = (const float*)d_in[5];
    const float* Wk  = (const float*)d_in[6];
    const float* bk  = (const float*)d_in[7];
    const float* Wq  = (const float*)d_in[8];
    const float* bq  = (const float*)d_in[9];
    const float* Wc  = (const float*)d_in[10];
    const float* bc  = (const float*)d_in[11];
    const float* Wm  = (const float*)d_in[12];
    const float* bm  = (const float*)d_in[13];
    const float* Wup = (const float*)d_in[14];
    const float* lnw = (const float*)d_in[15];
    const float* lnb = (const float*)d_in[16];
    const float* tau = (const float*)d_in[17];

    const size_t NE  = (size_t)B_ * NK_ * HD_;   // 8M elements
    const size_t NW  = (size_t)HD_ * HD_;        // 1M
    const size_t NC  = (size_t)B_ * KC_ * HD_;   // 256K

    // ---- workspace layout (bytes); three 16MB time-shared slots ----
    //   slotA: k16  -> QE   (QE written after KH-gemm consumed k16)
    //   slotB: v16  -> CU16 (CU written after VT-gemm consumed v16)
    //   slotC: q16  -> ATT  (ATT written after QE-gemm consumed q16)
    const size_t REQUIRED = 95944704;            // 91.5 MB
    if (ws_size < REQUIRED) {                    // diagnostic sentinel, no fault
        fill_sentinel<<<dim3((out_size + 255) / 256), dim3(256), 0, stream>>>((float*)d_out, out_size);
        return;
    }
    char* ws = (char*)d_ws;
    f16*  k16  = (f16*)(ws + 0);                 // slotA
    f16*  QE   = (f16*)(ws + 0);
    f16*  v16  = (f16*)(ws + 16777216);          // slotB
    f16*  CU16 = (f16*)(ws + 16777216);
    f16*  q16  = (f16*)(ws + 33554432);          // slotC
    f16*  ATT  = (f16*)(ws + 33554432);
    f16*  c16  = (f16*)(ws + 50331648);
    float* CHf = (float*)(ws + 50855936);
    f16*  wk16 = (f16*)(ws + 51904512);
    f16*  wq16 = (f16*)(ws + 54001664);
    f16*  wv16 = (f16*)(ws + 56098816);
    f16*  wc16 = (f16*)(ws + 58195968);
    f16*  wm16 = (f16*)(ws + 60293120);
    f16*  KH   = (f16*)(ws + 62390272);
    f16*  VT   = (f16*)(ws + 79167488);

    dim3 blk(256);
    auto cvt = [&](const float* in, f16* out, size_t n) {
        cvt_f32_f16<<<dim3((unsigned)(n / 1024)), blk, 0, stream>>>(in, out, (int)(n / 4));
    };
    cvt(k, k16, NE);
    cvt(v, v16, NE);
    cvt(q, q16, NE);
    cvt(c, c16, NC);
    cvt(Wk, wk16, NW);
    cvt(Wq, wq16, NW);
    cvt(Wv, wv16, NW);
    cvt(Wc, wc16, NW);
    cvt(Wm, wm16, NW);

    // KH[b,key,hd] = k·Wk^T + bk
    gemm_nt<1><<<dim3(8, 8, 8), blk, 0, stream>>>(k16, (long long)NK_ * HD_, wk16, 0,
        KH, (long long)NK_ * HD_, NK_, HD_, HD_, bk, nullptr, 0, nullptr);
    // VT[b,hd,key] = (v·Wv^T + bv)^T  (Wv as A-operand)
    gemm_nt<2><<<dim3(8, 8, 8), blk, 0, stream>>>(wv16, 0, v16, (long long)NK_ * HD_,
        VT, (long long)HD_ * NK_, HD_, NK_, HD_, bv, nullptr, 0, nullptr);
    // CH[b,c,hd] = c·Wc^T + bc (fp32)
    gemm_nt<0><<<dim3(8, 1, 8), blk, 0, stream>>>(c16, (long long)KC_ * HD_, wc16, 0,
        CHf, (long long)KC_ * HD_, KC_, HD_, HD_, bc, nullptr, 0, nullptr);
    // CU = Wup · CH  (f16)
    upsample_k<<<dim3(NQ_, B_), blk, 0, stream>>>(Wup, CHf, CU16);
    // QE[b,q,hd] = (q·Wq^T + bq + t·CU) * inv_sqrt_d/(1+t)
    gemm_nt<3><<<dim3(8, 8, 8), blk, 0, stream>>>(q16, (long long)NQ_ * HD_, wq16, 0,
        QE, (long long)NQ_ * HD_, NQ_, HD_, HD_, bq, CU16, (long long)NQ_ * HD_, tau);
    // fused attention -> ATT[b,q,hd] (f16)
    attn_k<<<dim3(NQ_ / 16, H_, B_), blk, 0, stream>>>(QE, KH, VT, lnw, lnb, ATT);
    // out = ATT·Wm^T + bm (fp32)
    gemm_nt<4><<<dim3(8, 8, 8), blk, 0, stream>>>(ATT, (long long)NQ_ * HD_, wm16, 0,
        d_out, (long long)NQ_ * HD_, NQ_, HD_, HD_, bm, nullptr, 0, nullptr);
}